// Round 3
// baseline (2310.602 us; speedup 1.0000x reference)
//
#include <hip/hip_runtime.h>

// Dtype-agnostic Gram-trick implementation.
//  probe: detect input dtype (bf16 vs f32) from bn_gamma bit patterns -> flag
//  convert_all: stage all inputs as canonical bf16 into Sbuf
//  sur_all -> Mbuf[b][1152][HW] bf16 (rows 0..127 cenx, 128..1151 sur)
//  gram (K-split + atomics) -> compact G: D1(128x128), D2(128x1024), S_j(256x256 x4)
//  qnorm/knorm: row norms via quadratic forms; score = q_w.D2.k_w^T
//  in_softmax (scale+InstanceNorm+softmax); attnW2; wfin (out_w folded)
//  y_gemm (the only big GEMM); bn_stats; bn_apply (bf16 or f32 store per flag)

#define HW 16384
typedef unsigned short u16;
typedef unsigned int u32;

// staging offsets (u16 elements)
#define S_CEN 0
#define S_QW 1048576
#define S_KW 1056768
#define S_VW 1581056
#define S_W1 2105344
#define S_B1 2142208
#define S_W2 2142336
#define S_B2 2143360
#define S_SW 2143392
#define S_OW 2143400
#define S_GAMMA 2208936
#define S_BETA 2209192
#define S_TOTAL 2209456  // padded to multiple of 8

// compact Gram layout per batch (f32 elements)
#define G_D1 0       // 128x128, stride 128
#define G_D2 16384   // 128x1024, stride 1024
#define G_S 147456   // 4 blocks of 256x256, stride 256
#define G_SZ 409600

__device__ __forceinline__ float b2f(u16 u) { return __uint_as_float(((u32)u) << 16); }
__device__ __forceinline__ u16 f2b(float f) {
  u32 u = __float_as_uint(f);
  return (u16)((u + 0x7FFFu + ((u >> 16) & 1u)) >> 16);  // RNE
}
__device__ __forceinline__ float wave_sum(float v) {
  #pragma unroll
  for (int off = 32; off > 0; off >>= 1) v += __shfl_xor(v, off, 64);
  return v;
}
__device__ __forceinline__ float wave_max(float v) {
  #pragma unroll
  for (int off = 32; off > 0; off >>= 1) v = fmaxf(v, __shfl_xor(v, off, 64));
  return v;
}
__device__ __forceinline__ void unpack8(uint4 v, float* f) {
  f[0] = __uint_as_float(v.x << 16); f[1] = __uint_as_float(v.x & 0xFFFF0000u);
  f[2] = __uint_as_float(v.y << 16); f[3] = __uint_as_float(v.y & 0xFFFF0000u);
  f[4] = __uint_as_float(v.z << 16); f[5] = __uint_as_float(v.z & 0xFFFF0000u);
  f[6] = __uint_as_float(v.w << 16); f[7] = __uint_as_float(v.w & 0xFFFF0000u);
}

// ------------------------------------------------------------ dtype probe
__global__ void probe(const u32* __restrict__ g, int* __restrict__ flag) {
  if (threadIdx.x == 0) {
    int ok = 1;
    #pragma unroll
    for (int i = 0; i < 4; i++) {
      u32 w = g[i];
      u32 lo = w & 0xFFFFu, hi = w >> 16;
      ok &= (lo >= 0x3E00u && lo <= 0x4100u) ? 1 : 0;  // gamma ~ 1.0 as bf16
      ok &= (hi >= 0x3E00u && hi <= 0x4100u) ? 1 : 0;
    }
    *flag = ok ? 0 : 1;  // 0 = bf16 inputs, 1 = f32 inputs
  }
}

// ------------------------------------------------------------ stage inputs -> bf16
__global__ __launch_bounds__(256) void convert_all(
    const void* p0, const void* p1, const void* p2, const void* p3,
    const void* p4, const void* p5, const void* p6, const void* p7,
    const void* p8, const void* p9, const void* p10, const void* p11,
    u16* __restrict__ S, const int* __restrict__ flag) {
  const void* src; int n; int off;
  switch (blockIdx.z) {
    case 0:  src = p0;  n = 1048576; off = S_CEN; break;
    case 1:  src = p1;  n = 8192;    off = S_QW; break;
    case 2:  src = p2;  n = 524288;  off = S_KW; break;
    case 3:  src = p3;  n = 524288;  off = S_VW; break;
    case 4:  src = p4;  n = 36864;   off = S_W1; break;
    case 5:  src = p5;  n = 128;     off = S_B1; break;
    case 6:  src = p6;  n = 1024;    off = S_W2; break;
    case 7:  src = p7;  n = 32;      off = S_B2; break;
    case 8:  src = p8;  n = 8;       off = S_SW; break;
    case 9:  src = p9;  n = 65536;   off = S_OW; break;
    case 10: src = p10; n = 256;     off = S_GAMMA; break;
    default: src = p11; n = 256;     off = S_BETA; break;
  }
  int idx = (blockIdx.x * 256 + threadIdx.x) * 4;
  if (idx >= n) return;
  u16* dst = S + off + idx;
  if (*flag) {
    float4 v = ((const float4*)src)[idx >> 2];
    dst[0] = f2b(v.x); dst[1] = f2b(v.y); dst[2] = f2b(v.z); dst[3] = f2b(v.w);
  } else {
    *(ushort4*)dst = ((const ushort4*)src)[idx >> 2];
  }
}

// -------------------------------------------------------------- sur + cenx -> Mbuf
__global__ __launch_bounds__(256) void sur_all(
    const u16* __restrict__ cen, const u16* __restrict__ w1g,
    const u16* __restrict__ b1g, const u16* __restrict__ w2g,
    const u16* __restrict__ b2g, const u16* __restrict__ swg,
    u16* __restrict__ Mbuf) {
  const int si = blockIdx.z;
  const int d = 1 << si;  // 1,2,4,8
  __shared__ float w1s[9216];  // [tap][ci][co]
  __shared__ float w2s[256];
  __shared__ float b1s[32];
  __shared__ float b2s[8];
  const int t = threadIdx.x;
  for (int e = t; e < 9216; e += 256) {
    int tap = e >> 10, rem = e & 1023, ci = rem >> 5, co = rem & 31;
    w1s[e] = b2f(w1g[si * 9216 + co * 288 + ci * 9 + tap]);
  }
  w2s[t] = b2f(w2g[si * 256 + t]);
  if (t < 32) b1s[t] = b2f(b1g[si * 32 + t]);
  if (t < 8) b2s[t] = b2f(b2g[si * 8 + t]);
  __syncthreads();

  const int b = blockIdx.y;
  const int s = blockIdx.x * 256 + t;
  const int h = s >> 7, w = s & 127;

  float s0 = b2f(swg[si * 2 + 0]), s1 = b2f(swg[si * 2 + 1]);
  float mx = fmaxf(s0, s1);
  float e0 = expf(s0 - mx), e1 = expf(s1 - mx);
  float w20 = e0 / (e0 + e1), w21 = e1 / (e0 + e1);

  const u16* cb = cen + (size_t)b * 32 * HW;

  // dilated 3x3 conv, ZERO padding
  float h1[32];
  #pragma unroll
  for (int i = 0; i < 32; i++) h1[i] = 0.f;
  for (int tap = 0; tap < 9; tap++) {
    int ky = tap / 3, kx = tap - ky * 3;
    int y = h + (ky - 1) * d, x = w + (kx - 1) * d;
    if (y < 0 || y >= 128 || x < 0 || x >= 128) continue;
    int off = y * 128 + x;
    const float* wt = &w1s[tap * 1024];
    for (int ci = 0; ci < 32; ci++) {
      float v = b2f(cb[(size_t)ci * HW + off]);
      #pragma unroll
      for (int co = 0; co < 32; co++) h1[co] = fmaf(v, wt[ci * 32 + co], h1[co]);
    }
  }
  #pragma unroll
  for (int i = 0; i < 32; i++) h1[i] = fmaxf(h1[i] + b1s[i], 0.f);

  // 8-way softmax * w2[0]
  float lg[8];
  #pragma unroll
  for (int k = 0; k < 8; k++) lg[k] = b2s[k];
  for (int ci = 0; ci < 32; ci++) {
    float v = h1[ci];
    #pragma unroll
    for (int k = 0; k < 8; k++) lg[k] = fmaf(v, w2s[k * 32 + ci], lg[k]);
  }
  float lm = lg[0];
  #pragma unroll
  for (int k = 1; k < 8; k++) lm = fmaxf(lm, lg[k]);
  float ls = 0.f;
  #pragma unroll
  for (int k = 0; k < 8; k++) { lg[k] = expf(lg[k] - lm); ls += lg[k]; }
  float inv = w20 / ls;
  #pragma unroll
  for (int k = 0; k < 8; k++) lg[k] *= inv;

  // reflect-padded neighbor offsets
  const int dy[8] = {-d, -d, -d, 0, 0, d, d, d};
  const int dx[8] = {-d, 0, d, -d, d, -d, 0, d};
  int offk[8];
  #pragma unroll
  for (int k = 0; k < 8; k++) {
    int y = h + dy[k]; y = y < 0 ? -y : (y > 127 ? 254 - y : y);
    int x = w + dx[k]; x = x < 0 ? -x : (x > 127 ? 254 - x : x);
    offk[k] = y * 128 + x;
  }
  u16* Mb = Mbuf + (size_t)b * 1152 * HW;
  for (int c = 0; c < 32; c++) {
    const u16* cc = cb + (size_t)c * HW;
    float cv = b2f(cc[s]);
    float nb[8];
    #pragma unroll
    for (int k = 0; k < 8; k++) nb[k] = b2f(cc[offk[k]]);
    float sx = 0.f, mn = 0.f;
    #pragma unroll
    for (int k = 0; k < 8; k++) { sx = fmaf(lg[k], nb[k], sx); mn += nb[k]; }
    float sumx = sx + cv * w21;
    Mb[(size_t)(32 * si + c) * HW + s] = f2b(mn * 0.125f * w20 + cv * w21);
    #pragma unroll
    for (int k = 0; k < 8; k++)
      Mb[(size_t)(128 + 256 * si + k * 32 + c) * HW + s] = f2b(nb[k] - sumx);
  }
}

// ------------------------------------------ Gram blocks (K-split, atomic accumulate)
__global__ __launch_bounds__(256) void gram(
    const u16* __restrict__ Mbuf, float* __restrict__ G) {
  const int tid = blockIdx.x;  // 0..24 block id
  const int ks = blockIdx.y;   // 0..15 K split
  const int b = blockIdx.z;
  int r0, c0, gstride; size_t goff;
  if (tid == 0) { r0 = 0; c0 = 0; goff = G_D1; gstride = 128; }
  else if (tid < 9) { r0 = 0; c0 = 128 * tid; goff = G_D2 + (size_t)(tid - 1) * 128; gstride = 1024; }
  else {
    int t2 = tid - 9; int j = t2 >> 2, p = (t2 >> 1) & 1, q = t2 & 1;
    r0 = 128 + 256 * j + 128 * p; c0 = 128 + 256 * j + 128 * q;
    goff = G_S + (size_t)j * 65536 + p * 128 * 256 + q * 128; gstride = 256;
  }
  const u16* Mb = Mbuf + (size_t)b * 1152 * HW;
  __shared__ u16 As[64][136];
  __shared__ u16 Bs[64][136];
  const int t = threadIdx.x, tx = t & 15, ty = t >> 4;
  float acc[8][8];
  #pragma unroll
  for (int i = 0; i < 8; i++)
    #pragma unroll
    for (int j = 0; j < 8; j++) acc[i][j] = 0.f;
  for (int s0 = ks * 1024; s0 < ks * 1024 + 1024; s0 += 64) {
    for (int e = t; e < 8192; e += 256) {
      int r = e >> 6, sc = e & 63;
      As[sc][r] = Mb[(size_t)(r0 + r) * HW + s0 + sc];
      Bs[sc][r] = Mb[(size_t)(c0 + r) * HW + s0 + sc];
    }
    __syncthreads();
    #pragma unroll 4
    for (int sc = 0; sc < 64; sc++) {
      uint4 av = *(const uint4*)&As[sc][ty * 8];
      uint4 bv = *(const uint4*)&Bs[sc][tx * 8];
      float a[8], bb[8];
      unpack8(av, a); unpack8(bv, bb);
      #pragma unroll
      for (int i = 0; i < 8; i++)
        #pragma unroll
        for (int j = 0; j < 8; j++) acc[i][j] = fmaf(a[i], bb[j], acc[i][j]);
    }
    __syncthreads();
  }
  float* Gb = G + (size_t)b * G_SZ + goff;
  #pragma unroll
  for (int i = 0; i < 8; i++)
    #pragma unroll
    for (int j = 0; j < 8; j++)
      atomicAdd(&Gb[(size_t)(ty * 8 + i) * gstride + tx * 8 + j], acc[i][j]);
}

// ------------------------------------------------------------------ Q row inv-norms
__global__ __launch_bounds__(64) void qnorm(
    const u16* __restrict__ qw, const float* __restrict__ G,
    float* __restrict__ invQ) {
  const int bn = blockIdx.x, b = bn >> 2, n = bn & 3;
  const int rq = threadIdx.x;  // flat row in head = 4*q1r + i
  const int i = rq & 3, q1r = rq >> 2;
  const u16* qr = qw + ((size_t)(i * 64) + 16 * n + q1r) * 32;
  float v[32];
  #pragma unroll
  for (int c = 0; c < 32; c++) v[c] = b2f(qr[c]);
  const float* D1 = G + (size_t)b * G_SZ;  // stride 128
  float ss = 0.f;
  for (int c = 0; c < 32; c++) {
    float tmp = 0.f;
    #pragma unroll
    for (int c2 = 0; c2 < 32; c2++) tmp = fmaf(v[c2], D1[(size_t)(32 * i + c2) * 128 + 32 * i + c], tmp);
    ss = fmaf(tmp, v[c], ss);
  }
  invQ[bn * 64 + rq] = 1.f / fmaxf(sqrtf(fmaxf(ss, 0.f)), 1e-12f);
}

// ------------------------------------------------------------------ K row inv-norms
__global__ __launch_bounds__(256) void knorm(
    const u16* __restrict__ kw, const float* __restrict__ G,
    float* __restrict__ invK) {
  const int rk = blockIdx.x, n = blockIdx.y, b = blockIdx.z;
  const int j = rk & 3, kk = rk >> 2;
  const u16* kr = kw + ((size_t)(j * 512) + 128 * n + kk) * 256;
  __shared__ float vs[256];
  const int t = threadIdx.x;
  vs[t] = b2f(kr[t]);
  __syncthreads();
  const float* S = G + (size_t)b * G_SZ + G_S + (size_t)j * 65536;  // 256x256
  float tmp = 0.f;
  for (int c2 = 0; c2 < 256; c2++) tmp = fmaf(vs[c2], S[(size_t)c2 * 256 + t], tmp);
  tmp *= vs[t];
  tmp = wave_sum(tmp);
  __shared__ float red[4];
  if ((t & 63) == 0) red[t >> 6] = tmp;
  __syncthreads();
  if (t == 0) {
    float tot = fmaxf(red[0] + red[1] + red[2] + red[3], 0.f);
    invK[(size_t)(b * 4 + n) * 512 + rk] = 1.f / fmaxf(sqrtf(tot), 1e-12f);
  }
}

// ---------------------------------------------------- score = q_w . D2 . k_w^T
__global__ __launch_bounds__(256) void score_asm(
    const u16* __restrict__ qw, const u16* __restrict__ kw,
    const float* __restrict__ G, float* __restrict__ score) {
  const int n = blockIdx.x, b = blockIdx.y;
  __shared__ float Ds[32][256];
  __shared__ float KDs[32][128];
  __shared__ float qws[16][32];
  const float* D2 = G + (size_t)b * G_SZ + G_D2;  // 128x1024
  float* sb = score + (size_t)(b * 4 + n) * 64 * 512;
  const int t = threadIdx.x;
  for (int i = 0; i < 4; i++) {
    for (int e = t; e < 512; e += 256) {
      int r = e >> 5, c = e & 31;
      qws[r][c] = b2f(qw[((size_t)(i * 64) + 16 * n + r) * 32 + c]);
    }
    for (int j = 0; j < 4; j++) {
      for (int e = t; e < 8192; e += 256) {
        int r = e >> 8, c = e & 255;
        Ds[r][c] = D2[(size_t)(32 * i + r) * 1024 + 256 * j + c];
      }
      __syncthreads();
      for (int e = t; e < 4096; e += 256) {
        int c = e >> 7, kk = e & 127;
        const u16* krow = kw + ((size_t)(j * 512) + 128 * n + kk) * 256;
        float acc = 0.f;
        for (int ch = 0; ch < 256; ch++) acc = fmaf(Ds[c][ch], b2f(krow[ch]), acc);
        KDs[c][kk] = acc;
      }
      __syncthreads();
      for (int e = t; e < 2048; e += 256) {
        int q1r = e >> 7, kk = e & 127;
        float acc = 0.f;
        #pragma unroll
        for (int c = 0; c < 32; c++) acc = fmaf(qws[q1r][c], KDs[c][kk], acc);
        sb[(size_t)(4 * q1r + i) * 512 + 4 * kk + j] = acc;
      }
      __syncthreads();
    }
  }
}

// ------------------------------------------ scale + InstanceNorm + row softmax
__global__ __launch_bounds__(256) void in_softmax(
    float* __restrict__ score, const float* __restrict__ invQ,
    const float* __restrict__ invK) {
  const int bn = blockIdx.x;
  float* sb = score + (size_t)bn * 64 * 512;
  const float* iQ = invQ + bn * 64;
  const float* iK = invK + bn * 512;
  const int t = threadIdx.x;
  float sum = 0.f, ss = 0.f;
  const float isc = 1.f / 128.f;
  for (int e = t; e < 32768; e += 256) {
    int q = e >> 9, kk = e & 511;
    float v = sb[e] * iQ[q] * iK[kk] * isc;
    sb[e] = v;
    sum += v; ss += v * v;
  }
  __shared__ float red[8];
  sum = wave_sum(sum); ss = wave_sum(ss);
  if ((t & 63) == 0) { red[t >> 6] = sum; red[4 + (t >> 6)] = ss; }
  __syncthreads();
  float mean = (red[0] + red[1] + red[2] + red[3]) * (1.f / 32768.f);
  float var = (red[4] + red[5] + red[6] + red[7]) * (1.f / 32768.f) - mean * mean;
  float istd = rsqrtf(var + 1e-5f);
  const int wv = t >> 6, lane = t & 63;
  for (int r = wv; r < 64; r += 4) {
    float z[8];
    float m = -1e30f;
    #pragma unroll
    for (int j = 0; j < 8; j++) {
      z[j] = (sb[(size_t)r * 512 + lane + 64 * j] - mean) * istd;
      m = fmaxf(m, z[j]);
    }
    m = wave_max(m);
    float sloc = 0.f;
    #pragma unroll
    for (int j = 0; j < 8; j++) { z[j] = expf(z[j] - m); sloc += z[j]; }
    sloc = wave_sum(sloc);
    float rinv = 1.f / sloc;
    #pragma unroll
    for (int j = 0; j < 8; j++) sb[(size_t)r * 512 + lane + 64 * j] = z[j] * rinv;
  }
}

// ------------------------------------------- W2[bn][q][j*256+ch] = attn . v_w
__global__ __launch_bounds__(256) void attnW2(
    const float* __restrict__ attn, const u16* __restrict__ vw,
    float* __restrict__ W2) {
  const int n = blockIdx.x, q0 = blockIdx.y * 8, b = blockIdx.z, bn = b * 4 + n;
  const float* ab = attn + (size_t)bn * 64 * 512;
  const int t = threadIdx.x;
  const int j = t >> 6, lane = t & 63;
  __shared__ float at_s[8][512];
  for (int e = t; e < 4096; e += 256) {
    int qg = e >> 9, kcol = e & 511;
    at_s[qg][kcol] = ab[(size_t)(q0 + qg) * 512 + kcol];
  }
  __syncthreads();
  float acc[8][4];
  #pragma unroll
  for (int qg = 0; qg < 8; qg++)
    #pragma unroll
    for (int cc = 0; cc < 4; cc++) acc[qg][cc] = 0.f;
  for (int kk = 0; kk < 128; kk++) {
    const u16* vrow = vw + ((size_t)(j * 512) + 128 * n + kk) * 256 + lane;
    float v0 = b2f(vrow[0]), v1 = b2f(vrow[64]), v2 = b2f(vrow[128]), v3 = b2f(vrow[192]);
    #pragma unroll
    for (int qg = 0; qg < 8; qg++) {
      float a = at_s[qg][4 * kk + j];
      acc[qg][0] = fmaf(a, v0, acc[qg][0]);
      acc[qg][1] = fmaf(a, v1, acc[qg][1]);
      acc[qg][2] = fmaf(a, v2, acc[qg][2]);
      acc[qg][3] = fmaf(a, v3, acc[qg][3]);
    }
  }
  #pragma unroll
  for (int qg = 0; qg < 8; qg++)
    #pragma unroll
    for (int cc = 0; cc < 4; cc++)
      W2[((size_t)bn * 64 + q0 + qg) * 1024 + j * 256 + lane + 64 * cc] = acc[qg][cc];
}

// ------------------------------------------------ Wfin[b][o][jc] = out_w . W2
__global__ __launch_bounds__(256) void wfin_k(
    const u16* __restrict__ ow, const float* __restrict__ W2,
    float* __restrict__ Wfin) {
  const int jc = blockIdx.x, b = blockIdx.y;
  __shared__ float col[256];
  const int t = threadIdx.x;
  col[t] = W2[((size_t)b * 256 + t) * 1024 + jc];
  __syncthreads();
  float acc = 0.f;
  const u16* owr = ow + (size_t)t * 256;
  for (int c = 0; c < 256; c++) acc = fmaf(b2f(owr[c]), col[c], acc);
  Wfin[((size_t)b * 256 + t) * 1024 + jc] = acc;
}

// ------------------------------------------------ y = Wfin @ sur_rows (bf16 out)
__global__ __launch_bounds__(256) void y_gemm(
    const float* __restrict__ Wfin, const u16* __restrict__ Mbuf,
    u16* __restrict__ ybuf) {
  const int b = blockIdx.z, row0 = blockIdx.y * 128, col0 = blockIdx.x * 128;
  __shared__ float As[64][132];
  __shared__ u16 Bs[64][128];
  const int t = threadIdx.x, tx = t & 15, ty = t >> 4;
  float acc[8][8];
  #pragma unroll
  for (int i = 0; i < 8; i++)
    #pragma unroll
    for (int j = 0; j < 8; j++) acc[i][j] = 0.f;
  const float* Ab = Wfin + (size_t)b * 256 * 1024;
  const u16* Mb = Mbuf + (size_t)b * 1152 * HW + (size_t)128 * HW;
  for (int k0 = 0; k0 < 1024; k0 += 64) {
    for (int e = t; e < 8192; e += 256) {
      int r = e >> 6, kc = e & 63;
      As[kc][r] = Ab[(size_t)(row0 + r) * 1024 + k0 + kc];
    }
    for (int e = t; e < 8192; e += 256) {
      int kc = e >> 7, c = e & 127;
      Bs[kc][c] = Mb[(size_t)(k0 + kc) * HW + col0 + c];
    }
    __syncthreads();
    #pragma unroll 4
    for (int kc = 0; kc < 64; kc++) {
      float4 a0 = *(const float4*)&As[kc][ty * 8];
      float4 a1 = *(const float4*)&As[kc][ty * 8 + 4];
      uint4 bv = *(const uint4*)&Bs[kc][tx * 8];
      float a[8] = {a0.x, a0.y, a0.z, a0.w, a1.x, a1.y, a1.z, a1.w};
      float bb[8];
      unpack8(bv, bb);
      #pragma unroll
      for (int i = 0; i < 8; i++)
        #pragma unroll
        for (int j = 0; j < 8; j++) acc[i][j] = fmaf(a[i], bb[j], acc[i][j]);
    }
    __syncthreads();
  }
  #pragma unroll
  for (int i = 0; i < 8; i++) {
    int row = row0 + ty * 8 + i;
    u32 p0 = (u32)f2b(acc[i][0]) | ((u32)f2b(acc[i][1]) << 16);
    u32 p1 = (u32)f2b(acc[i][2]) | ((u32)f2b(acc[i][3]) << 16);
    u32 p2 = (u32)f2b(acc[i][4]) | ((u32)f2b(acc[i][5]) << 16);
    u32 p3 = (u32)f2b(acc[i][6]) | ((u32)f2b(acc[i][7]) << 16);
    *(uint4*)(ybuf + ((size_t)b * 256 + row) * HW + col0 + tx * 8) = make_uint4(p0, p1, p2, p3);
  }
}

// ---------------------------------------------------------------- BatchNorm
__global__ __launch_bounds__(256) void bn_stats(
    const u16* __restrict__ y, float* __restrict__ st) {
  const int o = blockIdx.x;
  const int t = threadIdx.x;
  float sum = 0.f, ss = 0.f;
  for (int bb = 0; bb < 2; bb++) {
    const u16* p = y + ((size_t)bb * 256 + o) * HW;
    for (int e = t; e < HW / 8; e += 256) {
      uint4 v = ((const uint4*)p)[e];
      float f[8];
      unpack8(v, f);
      #pragma unroll
      for (int k = 0; k < 8; k++) { sum += f[k]; ss += f[k] * f[k]; }
    }
  }
  __shared__ float red[8];
  sum = wave_sum(sum); ss = wave_sum(ss);
  if ((t & 63) == 0) { red[t >> 6] = sum; red[4 + (t >> 6)] = ss; }
  __syncthreads();
  if (t == 0) {
    float mean = (red[0] + red[1] + red[2] + red[3]) / 32768.f;
    float var = (red[4] + red[5] + red[6] + red[7]) / 32768.f - mean * mean;
    st[o * 2] = mean;
    st[o * 2 + 1] = rsqrtf(var + 1e-5f);
  }
}

__global__ __launch_bounds__(256) void bn_apply(
    const u16* __restrict__ y, const float* __restrict__ st,
    const u16* __restrict__ gamma, const u16* __restrict__ beta,
    const int* __restrict__ flag, void* __restrict__ out) {
  const int idx8 = blockIdx.x * 256 + threadIdx.x;  // < 1048576
  const int r = idx8 >> 11;   // row in [0,512)
  const int o = r & 255;
  float mean = st[o * 2], istd = st[o * 2 + 1];
  float g = b2f(gamma[o]), be = b2f(beta[o]);
  uint4 v = ((const uint4*)y)[idx8];
  float f[8];
  unpack8(v, f);
  float rr[8];
  #pragma unroll
  for (int k = 0; k < 8; k++) rr[k] = fmaxf((f[k] - mean) * istd * g + be, 0.f);
  if (*flag) {
    float* of = (float*)out + (size_t)idx8 * 8;
    *(float4*)of = make_float4(rr[0], rr[1], rr[2], rr[3]);
    *(float4*)(of + 4) = make_float4(rr[4], rr[5], rr[6], rr[7]);
  } else {
    u32 p0 = (u32)f2b(rr[0]) | ((u32)f2b(rr[1]) << 16);
    u32 p1 = (u32)f2b(rr[2]) | ((u32)f2b(rr[3]) << 16);
    u32 p2 = (u32)f2b(rr[4]) | ((u32)f2b(rr[5]) << 16);
    u32 p3 = (u32)f2b(rr[6]) | ((u32)f2b(rr[7]) << 16);
    ((uint4*)out)[idx8] = make_uint4(p0, p1, p2, p3);
  }
}

// ----------------------------------------------------------------------------
extern "C" void kernel_launch(void* const* d_in, const int* in_sizes, int n_in,
                              void* d_out, int out_size, void* d_ws, size_t ws_size,
                              hipStream_t stream) {
  float* G     = (float*)d_ws;           // 819,200 f32 (2 x G_SZ)
  float* score = G + 819200;             // 262,144
  float* invQ  = score + 262144;         // 512
  float* invK  = invQ + 512;             // 4,096
  float* W2    = invK + 4096;            // 524,288
  float* Wfin  = W2 + 524288;            // 524,288
  float* bnst  = Wfin + 524288;          // 512
  int* flag    = (int*)(bnst + 512);     // 16
  u16* Sbuf    = (u16*)(flag + 16);      // S_TOTAL u16
  u16* Mbuf    = Sbuf + S_TOTAL;         // 37,748,736 u16
  u16* ybuf    = Mbuf + 37748736;        // 8,388,608 u16
  // total ~100.4 MiB

  probe<<<1, 64, 0, stream>>>((const u32*)d_in[10], flag);
  convert_all<<<dim3(1024, 1, 12), 256, 0, stream>>>(
      d_in[0], d_in[1], d_in[2], d_in[3], d_in[4], d_in[5], d_in[6], d_in[7],
      d_in[8], d_in[9], d_in[10], d_in[11], Sbuf, flag);

  sur_all<<<dim3(64, 2, 4), 256, 0, stream>>>(
      Sbuf + S_CEN, Sbuf + S_W1, Sbuf + S_B1, Sbuf + S_W2, Sbuf + S_B2,
      Sbuf + S_SW, Mbuf);
  hipMemsetAsync(G, 0, 819200 * sizeof(float), stream);
  gram<<<dim3(25, 16, 2), 256, 0, stream>>>(Mbuf, G);
  qnorm<<<8, 64, 0, stream>>>(Sbuf + S_QW, G, invQ);
  knorm<<<dim3(512, 4, 2), 256, 0, stream>>>(Sbuf + S_KW, G, invK);
  score_asm<<<dim3(4, 2), 256, 0, stream>>>(Sbuf + S_QW, Sbuf + S_KW, G, score);
  in_softmax<<<8, 256, 0, stream>>>(score, invQ, invK);
  attnW2<<<dim3(4, 8, 2), 256, 0, stream>>>(score, Sbuf + S_VW, W2);
  wfin_k<<<dim3(1024, 2), 256, 0, stream>>>(Sbuf + S_OW, W2, Wfin);
  y_gemm<<<dim3(128, 2, 2), 256, 0, stream>>>(Wfin, Mbuf, ybuf);
  bn_stats<<<256, 256, 0, stream>>>(ybuf, bnst);
  bn_apply<<<4096, 256, 0, stream>>>(ybuf, bnst, Sbuf + S_GAMMA, Sbuf + S_BETA,
                                     flag, d_out);
}

// Round 4
// 1379.635 us; speedup vs baseline: 1.6748x; 1.6748x over previous
//
#include <hip/hip_runtime.h>

// Dtype-agnostic Gram-trick implementation.
//  probe: detect input dtype (bf16 vs f32) from bn_gamma bit patterns -> flag
//  convert_all: stage all inputs as canonical bf16 into Sbuf
//  sur_all -> Mbuf[b][1152][HW] bf16 (rows 0..127 cenx, 128..1151 sur)
//  gram (K-split + atomics) -> compact G: D1(128x128), D2(128x1024), S_j(256x256 x4)
//  qnorm/knorm: row norms via quadratic forms
//  score2: per (b,n,j) block: KD = D2_j . k_w^T (tiled GEMM in LDS), then
//          score slice = blockdiag(q_w) . KD   [R3: was 8-block latency-bound, 984us]
//  in_softmax (scale+InstanceNorm+softmax); attnW2; wfin (out_w folded)
//  y_gemm (the only big GEMM); bn_stats; bn_apply (bf16 or f32 store per flag)

#define HW 16384
typedef unsigned short u16;
typedef unsigned int u32;

// staging offsets (u16 elements)
#define S_CEN 0
#define S_QW 1048576
#define S_KW 1056768
#define S_VW 1581056
#define S_W1 2105344
#define S_B1 2142208
#define S_W2 2142336
#define S_B2 2143360
#define S_SW 2143392
#define S_OW 2143400
#define S_GAMMA 2208936
#define S_BETA 2209192
#define S_TOTAL 2209456  // padded to multiple of 8

// compact Gram layout per batch (f32 elements)
#define G_D1 0       // 128x128, stride 128
#define G_D2 16384   // 128x1024, stride 1024
#define G_S 147456   // 4 blocks of 256x256, stride 256
#define G_SZ 409600

__device__ __forceinline__ float b2f(u16 u) { return __uint_as_float(((u32)u) << 16); }
__device__ __forceinline__ u16 f2b(float f) {
  u32 u = __float_as_uint(f);
  return (u16)((u + 0x7FFFu + ((u >> 16) & 1u)) >> 16);  // RNE
}
__device__ __forceinline__ float wave_sum(float v) {
  #pragma unroll
  for (int off = 32; off > 0; off >>= 1) v += __shfl_xor(v, off, 64);
  return v;
}
__device__ __forceinline__ float wave_max(float v) {
  #pragma unroll
  for (int off = 32; off > 0; off >>= 1) v = fmaxf(v, __shfl_xor(v, off, 64));
  return v;
}
__device__ __forceinline__ void unpack8(uint4 v, float* f) {
  f[0] = __uint_as_float(v.x << 16); f[1] = __uint_as_float(v.x & 0xFFFF0000u);
  f[2] = __uint_as_float(v.y << 16); f[3] = __uint_as_float(v.y & 0xFFFF0000u);
  f[4] = __uint_as_float(v.z << 16); f[5] = __uint_as_float(v.z & 0xFFFF0000u);
  f[6] = __uint_as_float(v.w << 16); f[7] = __uint_as_float(v.w & 0xFFFF0000u);
}

// ------------------------------------------------------------ dtype probe
__global__ void probe(const u32* __restrict__ g, int* __restrict__ flag) {
  if (threadIdx.x == 0) {
    int ok = 1;
    #pragma unroll
    for (int i = 0; i < 4; i++) {
      u32 w = g[i];
      u32 lo = w & 0xFFFFu, hi = w >> 16;
      ok &= (lo >= 0x3E00u && lo <= 0x4100u) ? 1 : 0;  // gamma ~ 1.0 as bf16
      ok &= (hi >= 0x3E00u && hi <= 0x4100u) ? 1 : 0;
    }
    *flag = ok ? 0 : 1;  // 0 = bf16 inputs, 1 = f32 inputs
  }
}

// ------------------------------------------------------------ stage inputs -> bf16
__global__ __launch_bounds__(256) void convert_all(
    const void* p0, const void* p1, const void* p2, const void* p3,
    const void* p4, const void* p5, const void* p6, const void* p7,
    const void* p8, const void* p9, const void* p10, const void* p11,
    u16* __restrict__ S, const int* __restrict__ flag) {
  const void* src; int n; int off;
  switch (blockIdx.z) {
    case 0:  src = p0;  n = 1048576; off = S_CEN; break;
    case 1:  src = p1;  n = 8192;    off = S_QW; break;
    case 2:  src = p2;  n = 524288;  off = S_KW; break;
    case 3:  src = p3;  n = 524288;  off = S_VW; break;
    case 4:  src = p4;  n = 36864;   off = S_W1; break;
    case 5:  src = p5;  n = 128;     off = S_B1; break;
    case 6:  src = p6;  n = 1024;    off = S_W2; break;
    case 7:  src = p7;  n = 32;      off = S_B2; break;
    case 8:  src = p8;  n = 8;       off = S_SW; break;
    case 9:  src = p9;  n = 65536;   off = S_OW; break;
    case 10: src = p10; n = 256;     off = S_GAMMA; break;
    default: src = p11; n = 256;     off = S_BETA; break;
  }
  int idx = (blockIdx.x * 256 + threadIdx.x) * 4;
  if (idx >= n) return;
  u16* dst = S + off + idx;
  if (*flag) {
    float4 v = ((const float4*)src)[idx >> 2];
    dst[0] = f2b(v.x); dst[1] = f2b(v.y); dst[2] = f2b(v.z); dst[3] = f2b(v.w);
  } else {
    *(ushort4*)dst = ((const ushort4*)src)[idx >> 2];
  }
}

// -------------------------------------------------------------- sur + cenx -> Mbuf
__global__ __launch_bounds__(256) void sur_all(
    const u16* __restrict__ cen, const u16* __restrict__ w1g,
    const u16* __restrict__ b1g, const u16* __restrict__ w2g,
    const u16* __restrict__ b2g, const u16* __restrict__ swg,
    u16* __restrict__ Mbuf) {
  const int si = blockIdx.z;
  const int d = 1 << si;  // 1,2,4,8
  __shared__ float w1s[9216];  // [tap][ci][co]
  __shared__ float w2s[256];
  __shared__ float b1s[32];
  __shared__ float b2s[8];
  const int t = threadIdx.x;
  for (int e = t; e < 9216; e += 256) {
    int tap = e >> 10, rem = e & 1023, ci = rem >> 5, co = rem & 31;
    w1s[e] = b2f(w1g[si * 9216 + co * 288 + ci * 9 + tap]);
  }
  w2s[t] = b2f(w2g[si * 256 + t]);
  if (t < 32) b1s[t] = b2f(b1g[si * 32 + t]);
  if (t < 8) b2s[t] = b2f(b2g[si * 8 + t]);
  __syncthreads();

  const int b = blockIdx.y;
  const int s = blockIdx.x * 256 + t;
  const int h = s >> 7, w = s & 127;

  float s0 = b2f(swg[si * 2 + 0]), s1 = b2f(swg[si * 2 + 1]);
  float mx = fmaxf(s0, s1);
  float e0 = expf(s0 - mx), e1 = expf(s1 - mx);
  float w20 = e0 / (e0 + e1), w21 = e1 / (e0 + e1);

  const u16* cb = cen + (size_t)b * 32 * HW;

  // dilated 3x3 conv, ZERO padding
  float h1[32];
  #pragma unroll
  for (int i = 0; i < 32; i++) h1[i] = 0.f;
  for (int tap = 0; tap < 9; tap++) {
    int ky = tap / 3, kx = tap - ky * 3;
    int y = h + (ky - 1) * d, x = w + (kx - 1) * d;
    if (y < 0 || y >= 128 || x < 0 || x >= 128) continue;
    int off = y * 128 + x;
    const float* wt = &w1s[tap * 1024];
    for (int ci = 0; ci < 32; ci++) {
      float v = b2f(cb[(size_t)ci * HW + off]);
      #pragma unroll
      for (int co = 0; co < 32; co++) h1[co] = fmaf(v, wt[ci * 32 + co], h1[co]);
    }
  }
  #pragma unroll
  for (int i = 0; i < 32; i++) h1[i] = fmaxf(h1[i] + b1s[i], 0.f);

  // 8-way softmax * w2[0]
  float lg[8];
  #pragma unroll
  for (int k = 0; k < 8; k++) lg[k] = b2s[k];
  for (int ci = 0; ci < 32; ci++) {
    float v = h1[ci];
    #pragma unroll
    for (int k = 0; k < 8; k++) lg[k] = fmaf(v, w2s[k * 32 + ci], lg[k]);
  }
  float lm = lg[0];
  #pragma unroll
  for (int k = 1; k < 8; k++) lm = fmaxf(lm, lg[k]);
  float ls = 0.f;
  #pragma unroll
  for (int k = 0; k < 8; k++) { lg[k] = expf(lg[k] - lm); ls += lg[k]; }
  float inv = w20 / ls;
  #pragma unroll
  for (int k = 0; k < 8; k++) lg[k] *= inv;

  // reflect-padded neighbor offsets
  const int dy[8] = {-d, -d, -d, 0, 0, d, d, d};
  const int dx[8] = {-d, 0, d, -d, d, -d, 0, d};
  int offk[8];
  #pragma unroll
  for (int k = 0; k < 8; k++) {
    int y = h + dy[k]; y = y < 0 ? -y : (y > 127 ? 254 - y : y);
    int x = w + dx[k]; x = x < 0 ? -x : (x > 127 ? 254 - x : x);
    offk[k] = y * 128 + x;
  }
  u16* Mb = Mbuf + (size_t)b * 1152 * HW;
  for (int c = 0; c < 32; c++) {
    const u16* cc = cb + (size_t)c * HW;
    float cv = b2f(cc[s]);
    float nb[8];
    #pragma unroll
    for (int k = 0; k < 8; k++) nb[k] = b2f(cc[offk[k]]);
    float sx = 0.f, mn = 0.f;
    #pragma unroll
    for (int k = 0; k < 8; k++) { sx = fmaf(lg[k], nb[k], sx); mn += nb[k]; }
    float sumx = sx + cv * w21;
    Mb[(size_t)(32 * si + c) * HW + s] = f2b(mn * 0.125f * w20 + cv * w21);
    #pragma unroll
    for (int k = 0; k < 8; k++)
      Mb[(size_t)(128 + 256 * si + k * 32 + c) * HW + s] = f2b(nb[k] - sumx);
  }
}

// ------------------------------------------ Gram blocks (K-split, atomic accumulate)
__global__ __launch_bounds__(256) void gram(
    const u16* __restrict__ Mbuf, float* __restrict__ G) {
  const int tid = blockIdx.x;  // 0..24 block id
  const int ks = blockIdx.y;   // 0..15 K split
  const int b = blockIdx.z;
  int r0, c0, gstride; size_t goff;
  if (tid == 0) { r0 = 0; c0 = 0; goff = G_D1; gstride = 128; }
  else if (tid < 9) { r0 = 0; c0 = 128 * tid; goff = G_D2 + (size_t)(tid - 1) * 128; gstride = 1024; }
  else {
    int t2 = tid - 9; int j = t2 >> 2, p = (t2 >> 1) & 1, q = t2 & 1;
    r0 = 128 + 256 * j + 128 * p; c0 = 128 + 256 * j + 128 * q;
    goff = G_S + (size_t)j * 65536 + p * 128 * 256 + q * 128; gstride = 256;
  }
  const u16* Mb = Mbuf + (size_t)b * 1152 * HW;
  __shared__ u16 As[64][136];
  __shared__ u16 Bs[64][136];
  const int t = threadIdx.x, tx = t & 15, ty = t >> 4;
  float acc[8][8];
  #pragma unroll
  for (int i = 0; i < 8; i++)
    #pragma unroll
    for (int j = 0; j < 8; j++) acc[i][j] = 0.f;
  for (int s0 = ks * 1024; s0 < ks * 1024 + 1024; s0 += 64) {
    for (int e = t; e < 8192; e += 256) {
      int r = e >> 6, sc = e & 63;
      As[sc][r] = Mb[(size_t)(r0 + r) * HW + s0 + sc];
      Bs[sc][r] = Mb[(size_t)(c0 + r) * HW + s0 + sc];
    }
    __syncthreads();
    #pragma unroll 4
    for (int sc = 0; sc < 64; sc++) {
      uint4 av = *(const uint4*)&As[sc][ty * 8];
      uint4 bv = *(const uint4*)&Bs[sc][tx * 8];
      float a[8], bb[8];
      unpack8(av, a); unpack8(bv, bb);
      #pragma unroll
      for (int i = 0; i < 8; i++)
        #pragma unroll
        for (int j = 0; j < 8; j++) acc[i][j] = fmaf(a[i], bb[j], acc[i][j]);
    }
    __syncthreads();
  }
  float* Gb = G + (size_t)b * G_SZ + goff;
  #pragma unroll
  for (int i = 0; i < 8; i++)
    #pragma unroll
    for (int j = 0; j < 8; j++)
      atomicAdd(&Gb[(size_t)(ty * 8 + i) * gstride + tx * 8 + j], acc[i][j]);
}

// ------------------------------------------------------------------ Q row inv-norms
__global__ __launch_bounds__(64) void qnorm(
    const u16* __restrict__ qw, const float* __restrict__ G,
    float* __restrict__ invQ) {
  const int bn = blockIdx.x, b = bn >> 2, n = bn & 3;
  const int rq = threadIdx.x;  // flat row in head = 4*q1r + i
  const int i = rq & 3, q1r = rq >> 2;
  const u16* qr = qw + ((size_t)(i * 64) + 16 * n + q1r) * 32;
  float v[32];
  #pragma unroll
  for (int c = 0; c < 32; c++) v[c] = b2f(qr[c]);
  const float* D1 = G + (size_t)b * G_SZ;  // stride 128
  float ss = 0.f;
  for (int c = 0; c < 32; c++) {
    float tmp = 0.f;
    #pragma unroll
    for (int c2 = 0; c2 < 32; c2++) tmp = fmaf(v[c2], D1[(size_t)(32 * i + c2) * 128 + 32 * i + c], tmp);
    ss = fmaf(tmp, v[c], ss);
  }
  invQ[bn * 64 + rq] = 1.f / fmaxf(sqrtf(fmaxf(ss, 0.f)), 1e-12f);
}

// ------------------------------------------------------------------ K row inv-norms
__global__ __launch_bounds__(256) void knorm(
    const u16* __restrict__ kw, const float* __restrict__ G,
    float* __restrict__ invK) {
  const int rk = blockIdx.x, n = blockIdx.y, b = blockIdx.z;
  const int j = rk & 3, kk = rk >> 2;
  const u16* kr = kw + ((size_t)(j * 512) + 128 * n + kk) * 256;
  __shared__ float vs[256];
  const int t = threadIdx.x;
  vs[t] = b2f(kr[t]);
  __syncthreads();
  const float* S = G + (size_t)b * G_SZ + G_S + (size_t)j * 65536;  // 256x256
  float tmp = 0.f;
  for (int c2 = 0; c2 < 256; c2++) tmp = fmaf(vs[c2], S[(size_t)c2 * 256 + t], tmp);
  tmp *= vs[t];
  tmp = wave_sum(tmp);
  __shared__ float red[4];
  if ((t & 63) == 0) red[t >> 6] = tmp;
  __syncthreads();
  if (t == 0) {
    float tot = fmaxf(red[0] + red[1] + red[2] + red[3], 0.f);
    invK[(size_t)(b * 4 + n) * 512 + rk] = 1.f / fmaxf(sqrtf(tot), 1e-12f);
  }
}

// ------------------- score2: per (j,n,b): KD = D2_j . kw^T, then blockdiag(q_w).KD
__global__ __launch_bounds__(256) void score2(
    const u16* __restrict__ qw, const u16* __restrict__ kw,
    const float* __restrict__ G, float* __restrict__ score) {
  const int j = blockIdx.x, n = blockIdx.y, b = blockIdx.z;
  const float* D2 = G + (size_t)b * G_SZ + G_D2;          // 128 x 1024
  const u16* kwb = kw + ((size_t)(j * 512) + 128 * n) * 256;  // 128 rows x 256
  __shared__ float As[64][132];   // As[kc][R] = D2[R][j*256+ch0+kc]
  __shared__ u16 Bs[64][128];     // Bs[kc][kk] = kwb[kk][ch0+kc]
  __shared__ float KD[128][132];  // KD[R][kk]
  __shared__ float qws[64][32];   // qws[4*q1r+i][c]
  const int t = threadIdx.x, tx = t & 15, ty = t >> 4;
  float acc[8][8];
  #pragma unroll
  for (int i = 0; i < 8; i++)
    #pragma unroll
    for (int jj = 0; jj < 8; jj++) acc[i][jj] = 0.f;
  for (int ch0 = 0; ch0 < 256; ch0 += 64) {
    for (int e = t; e < 8192; e += 256) {
      int r = e >> 6, kc = e & 63;
      As[kc][r] = D2[(size_t)r * 1024 + j * 256 + ch0 + kc];
      Bs[kc][r] = kwb[(size_t)r * 256 + ch0 + kc];
    }
    __syncthreads();
    #pragma unroll 4
    for (int kc = 0; kc < 64; kc++) {
      float4 a0 = *(const float4*)&As[kc][ty * 8];
      float4 a1 = *(const float4*)&As[kc][ty * 8 + 4];
      uint4 bv = *(const uint4*)&Bs[kc][tx * 8];
      float a[8] = {a0.x, a0.y, a0.z, a0.w, a1.x, a1.y, a1.z, a1.w};
      float bb[8];
      unpack8(bv, bb);
      #pragma unroll
      for (int i = 0; i < 8; i++)
        #pragma unroll
        for (int jj = 0; jj < 8; jj++) acc[i][jj] = fmaf(a[i], bb[jj], acc[i][jj]);
    }
    __syncthreads();
  }
  #pragma unroll
  for (int i = 0; i < 8; i++)
    #pragma unroll
    for (int jj = 0; jj < 8; jj++) KD[ty * 8 + i][tx * 8 + jj] = acc[i][jj];
  for (int e = t; e < 2048; e += 256) {
    int q = e >> 5, c = e & 31;
    int i = q & 3, q1r = q >> 2;
    qws[q][c] = b2f(qw[((size_t)(i * 64) + 16 * n + q1r) * 32 + c]);
  }
  __syncthreads();
  float* sb = score + (size_t)(b * 4 + n) * 64 * 512;
  for (int e = t; e < 8192; e += 256) {
    int q = e >> 7, kk = e & 127;
    int i = q & 3;
    float s = 0.f;
    #pragma unroll
    for (int c = 0; c < 32; c++) s = fmaf(qws[q][c], KD[i * 32 + c][kk], s);
    sb[(size_t)q * 512 + 4 * kk + j] = s;
  }
}

// ------------------------------------------ scale + InstanceNorm + row softmax
__global__ __launch_bounds__(256) void in_softmax(
    float* __restrict__ score, const float* __restrict__ invQ,
    const float* __restrict__ invK) {
  const int bn = blockIdx.x;
  float* sb = score + (size_t)bn * 64 * 512;
  const float* iQ = invQ + bn * 64;
  const float* iK = invK + bn * 512;
  const int t = threadIdx.x;
  float sum = 0.f, ss = 0.f;
  const float isc = 1.f / 128.f;
  for (int e = t; e < 32768; e += 256) {
    int q = e >> 9, kk = e & 511;
    float v = sb[e] * iQ[q] * iK[kk] * isc;
    sb[e] = v;
    sum += v; ss += v * v;
  }
  __shared__ float red[8];
  sum = wave_sum(sum); ss = wave_sum(ss);
  if ((t & 63) == 0) { red[t >> 6] = sum; red[4 + (t >> 6)] = ss; }
  __syncthreads();
  float mean = (red[0] + red[1] + red[2] + red[3]) * (1.f / 32768.f);
  float var = (red[4] + red[5] + red[6] + red[7]) * (1.f / 32768.f) - mean * mean;
  float istd = rsqrtf(var + 1e-5f);
  const int wv = t >> 6, lane = t & 63;
  for (int r = wv; r < 64; r += 4) {
    float z[8];
    float m = -1e30f;
    #pragma unroll
    for (int j = 0; j < 8; j++) {
      z[j] = (sb[(size_t)r * 512 + lane + 64 * j] - mean) * istd;
      m = fmaxf(m, z[j]);
    }
    m = wave_max(m);
    float sloc = 0.f;
    #pragma unroll
    for (int j = 0; j < 8; j++) { z[j] = expf(z[j] - m); sloc += z[j]; }
    sloc = wave_sum(sloc);
    float rinv = 1.f / sloc;
    #pragma unroll
    for (int j = 0; j < 8; j++) sb[(size_t)r * 512 + lane + 64 * j] = z[j] * rinv;
  }
}

// ------------------------------------------- W2[bn][q][j*256+ch] = attn . v_w
__global__ __launch_bounds__(256) void attnW2(
    const float* __restrict__ attn, const u16* __restrict__ vw,
    float* __restrict__ W2) {
  const int n = blockIdx.x, q0 = blockIdx.y * 8, b = blockIdx.z, bn = b * 4 + n;
  const float* ab = attn + (size_t)bn * 64 * 512;
  const int t = threadIdx.x;
  const int j = t >> 6, lane = t & 63;
  __shared__ float at_s[8][512];
  for (int e = t; e < 4096; e += 256) {
    int qg = e >> 9, kcol = e & 511;
    at_s[qg][kcol] = ab[(size_t)(q0 + qg) * 512 + kcol];
  }
  __syncthreads();
  float acc[8][4];
  #pragma unroll
  for (int qg = 0; qg < 8; qg++)
    #pragma unroll
    for (int cc = 0; cc < 4; cc++) acc[qg][cc] = 0.f;
  for (int kk = 0; kk < 128; kk++) {
    const u16* vrow = vw + ((size_t)(j * 512) + 128 * n + kk) * 256 + lane;
    float v0 = b2f(vrow[0]), v1 = b2f(vrow[64]), v2 = b2f(vrow[128]), v3 = b2f(vrow[192]);
    #pragma unroll
    for (int qg = 0; qg < 8; qg++) {
      float a = at_s[qg][4 * kk + j];
      acc[qg][0] = fmaf(a, v0, acc[qg][0]);
      acc[qg][1] = fmaf(a, v1, acc[qg][1]);
      acc[qg][2] = fmaf(a, v2, acc[qg][2]);
      acc[qg][3] = fmaf(a, v3, acc[qg][3]);
    }
  }
  #pragma unroll
  for (int qg = 0; qg < 8; qg++)
    #pragma unroll
    for (int cc = 0; cc < 4; cc++)
      W2[((size_t)bn * 64 + q0 + qg) * 1024 + j * 256 + lane + 64 * cc] = acc[qg][cc];
}

// ------------------------------------------------ Wfin[b][o][jc] = out_w . W2
__global__ __launch_bounds__(256) void wfin_k(
    const u16* __restrict__ ow, const float* __restrict__ W2,
    float* __restrict__ Wfin) {
  const int jc = blockIdx.x, b = blockIdx.y;
  __shared__ float col[256];
  const int t = threadIdx.x;
  col[t] = W2[((size_t)b * 256 + t) * 1024 + jc];
  __syncthreads();
  float acc = 0.f;
  const u16* owr = ow + (size_t)t * 256;
  for (int c = 0; c < 256; c++) acc = fmaf(b2f(owr[c]), col[c], acc);
  Wfin[((size_t)b * 256 + t) * 1024 + jc] = acc;
}

// ------------------------------------------------ y = Wfin @ sur_rows (bf16 out)
__global__ __launch_bounds__(256) void y_gemm(
    const float* __restrict__ Wfin, const u16* __restrict__ Mbuf,
    u16* __restrict__ ybuf) {
  const int b = blockIdx.z, row0 = blockIdx.y * 128, col0 = blockIdx.x * 128;
  __shared__ float As[64][132];
  __shared__ u16 Bs[64][128];
  const int t = threadIdx.x, tx = t & 15, ty = t >> 4;
  float acc[8][8];
  #pragma unroll
  for (int i = 0; i < 8; i++)
    #pragma unroll
    for (int j = 0; j < 8; j++) acc[i][j] = 0.f;
  const float* Ab = Wfin + (size_t)b * 256 * 1024;
  const u16* Mb = Mbuf + (size_t)b * 1152 * HW + (size_t)128 * HW;
  for (int k0 = 0; k0 < 1024; k0 += 64) {
    for (int e = t; e < 8192; e += 256) {
      int r = e >> 6, kc = e & 63;
      As[kc][r] = Ab[(size_t)(row0 + r) * 1024 + k0 + kc];
    }
    for (int e = t; e < 8192; e += 256) {
      int kc = e >> 7, c = e & 127;
      Bs[kc][c] = Mb[(size_t)(k0 + kc) * HW + col0 + c];
    }
    __syncthreads();
    #pragma unroll 4
    for (int kc = 0; kc < 64; kc++) {
      float4 a0 = *(const float4*)&As[kc][ty * 8];
      float4 a1 = *(const float4*)&As[kc][ty * 8 + 4];
      uint4 bv = *(const uint4*)&Bs[kc][tx * 8];
      float a[8] = {a0.x, a0.y, a0.z, a0.w, a1.x, a1.y, a1.z, a1.w};
      float bb[8];
      unpack8(bv, bb);
      #pragma unroll
      for (int i = 0; i < 8; i++)
        #pragma unroll
        for (int j = 0; j < 8; j++) acc[i][j] = fmaf(a[i], bb[j], acc[i][j]);
    }
    __syncthreads();
  }
  #pragma unroll
  for (int i = 0; i < 8; i++) {
    int row = row0 + ty * 8 + i;
    u32 p0 = (u32)f2b(acc[i][0]) | ((u32)f2b(acc[i][1]) << 16);
    u32 p1 = (u32)f2b(acc[i][2]) | ((u32)f2b(acc[i][3]) << 16);
    u32 p2 = (u32)f2b(acc[i][4]) | ((u32)f2b(acc[i][5]) << 16);
    u32 p3 = (u32)f2b(acc[i][6]) | ((u32)f2b(acc[i][7]) << 16);
    *(uint4*)(ybuf + ((size_t)b * 256 + row) * HW + col0 + tx * 8) = make_uint4(p0, p1, p2, p3);
  }
}

// ---------------------------------------------------------------- BatchNorm
__global__ __launch_bounds__(256) void bn_stats(
    const u16* __restrict__ y, float* __restrict__ st) {
  const int o = blockIdx.x;
  const int t = threadIdx.x;
  float sum = 0.f, ss = 0.f;
  for (int bb = 0; bb < 2; bb++) {
    const u16* p = y + ((size_t)bb * 256 + o) * HW;
    for (int e = t; e < HW / 8; e += 256) {
      uint4 v = ((const uint4*)p)[e];
      float f[8];
      unpack8(v, f);
      #pragma unroll
      for (int k = 0; k < 8; k++) { sum += f[k]; ss += f[k] * f[k]; }
    }
  }
  __shared__ float red[8];
  sum = wave_sum(sum); ss = wave_sum(ss);
  if ((t & 63) == 0) { red[t >> 6] = sum; red[4 + (t >> 6)] = ss; }
  __syncthreads();
  if (t == 0) {
    float mean = (red[0] + red[1] + red[2] + red[3]) / 32768.f;
    float var = (red[4] + red[5] + red[6] + red[7]) / 32768.f - mean * mean;
    st[o * 2] = mean;
    st[o * 2 + 1] = rsqrtf(var + 1e-5f);
  }
}

__global__ __launch_bounds__(256) void bn_apply(
    const u16* __restrict__ y, const float* __restrict__ st,
    const u16* __restrict__ gamma, const u16* __restrict__ beta,
    const int* __restrict__ flag, void* __restrict__ out) {
  const int idx8 = blockIdx.x * 256 + threadIdx.x;  // < 1048576
  const int r = idx8 >> 11;   // row in [0,512)
  const int o = r & 255;
  float mean = st[o * 2], istd = st[o * 2 + 1];
  float g = b2f(gamma[o]), be = b2f(beta[o]);
  uint4 v = ((const uint4*)y)[idx8];
  float f[8];
  unpack8(v, f);
  float rr[8];
  #pragma unroll
  for (int k = 0; k < 8; k++) rr[k] = fmaxf((f[k] - mean) * istd * g + be, 0.f);
  if (*flag) {
    float* of = (float*)out + (size_t)idx8 * 8;
    *(float4*)of = make_float4(rr[0], rr[1], rr[2], rr[3]);
    *(float4*)(of + 4) = make_float4(rr[4], rr[5], rr[6], rr[7]);
  } else {
    u32 p0 = (u32)f2b(rr[0]) | ((u32)f2b(rr[1]) << 16);
    u32 p1 = (u32)f2b(rr[2]) | ((u32)f2b(rr[3]) << 16);
    u32 p2 = (u32)f2b(rr[4]) | ((u32)f2b(rr[5]) << 16);
    u32 p3 = (u32)f2b(rr[6]) | ((u32)f2b(rr[7]) << 16);
    ((uint4*)out)[idx8] = make_uint4(p0, p1, p2, p3);
  }
}

// ----------------------------------------------------------------------------
extern "C" void kernel_launch(void* const* d_in, const int* in_sizes, int n_in,
                              void* d_out, int out_size, void* d_ws, size_t ws_size,
                              hipStream_t stream) {
  float* G     = (float*)d_ws;           // 819,200 f32 (2 x G_SZ)
  float* score = G + 819200;             // 262,144
  float* invQ  = score + 262144;         // 512
  float* invK  = invQ + 512;             // 4,096
  float* W2    = invK + 4096;            // 524,288
  float* Wfin  = W2 + 524288;            // 524,288
  float* bnst  = Wfin + 524288;          // 512
  int* flag    = (int*)(bnst + 512);     // 16
  u16* Sbuf    = (u16*)(flag + 16);      // S_TOTAL u16
  u16* Mbuf    = Sbuf + S_TOTAL;         // 37,748,736 u16
  u16* ybuf    = Mbuf + 37748736;        // 8,388,608 u16
  // total ~100.4 MiB

  probe<<<1, 64, 0, stream>>>((const u32*)d_in[10], flag);
  convert_all<<<dim3(1024, 1, 12), 256, 0, stream>>>(
      d_in[0], d_in[1], d_in[2], d_in[3], d_in[4], d_in[5], d_in[6], d_in[7],
      d_in[8], d_in[9], d_in[10], d_in[11], Sbuf, flag);

  sur_all<<<dim3(64, 2, 4), 256, 0, stream>>>(
      Sbuf + S_CEN, Sbuf + S_W1, Sbuf + S_B1, Sbuf + S_W2, Sbuf + S_B2,
      Sbuf + S_SW, Mbuf);
  hipMemsetAsync(G, 0, 819200 * sizeof(float), stream);
  gram<<<dim3(25, 16, 2), 256, 0, stream>>>(Mbuf, G);
  qnorm<<<8, 64, 0, stream>>>(Sbuf + S_QW, G, invQ);
  knorm<<<dim3(512, 4, 2), 256, 0, stream>>>(Sbuf + S_KW, G, invK);
  score2<<<dim3(4, 4, 2), 256, 0, stream>>>(Sbuf + S_QW, Sbuf + S_KW, G, score);
  in_softmax<<<8, 256, 0, stream>>>(score, invQ, invK);
  attnW2<<<dim3(4, 8, 2), 256, 0, stream>>>(score, Sbuf + S_VW, W2);
  wfin_k<<<dim3(1024, 2), 256, 0, stream>>>(Sbuf + S_OW, W2, Wfin);
  y_gemm<<<dim3(128, 2, 2), 256, 0, stream>>>(Wfin, Mbuf, ybuf);
  bn_stats<<<256, 256, 0, stream>>>(ybuf, bnst);
  bn_apply<<<4096, 256, 0, stream>>>(ybuf, bnst, Sbuf + S_GAMMA, Sbuf + S_BETA,
                                     flag, d_out);
}

// Round 5
// 626.349 us; speedup vs baseline: 3.6890x; 2.2027x over previous
//
#include <hip/hip_runtime.h>

// Gram-trick + MFMA. R4 history: score2 fix 2310->1380us; gram was 765us VALU-bound
// (MfmaUtil=0). This round: gram and y_gemm on mfma_f32_16x16x32_bf16;
// wfin_k emits bf16 A for y_gemm.

#define HW 16384
typedef unsigned short u16;
typedef unsigned int u32;
typedef __attribute__((ext_vector_type(8))) short short8;  // 8 bf16 = 4 VGPRs
typedef __attribute__((ext_vector_type(4))) float f32x4;

// staging offsets (u16 elements)
#define S_CEN 0
#define S_QW 1048576
#define S_KW 1056768
#define S_VW 1581056
#define S_W1 2105344
#define S_B1 2142208
#define S_W2 2142336
#define S_B2 2143360
#define S_SW 2143392
#define S_OW 2143400
#define S_GAMMA 2208936
#define S_BETA 2209192
#define S_TOTAL 2209456

// compact Gram layout per batch (f32 elements)
#define G_D1 0       // 128x128, stride 128
#define G_D2 16384   // 128x1024, stride 1024
#define G_S 147456   // 4 blocks of 256x256, stride 256
#define G_SZ 409600

__device__ __forceinline__ float b2f(u16 u) { return __uint_as_float(((u32)u) << 16); }
__device__ __forceinline__ u16 f2b(float f) {
  u32 u = __float_as_uint(f);
  return (u16)((u + 0x7FFFu + ((u >> 16) & 1u)) >> 16);  // RNE
}
__device__ __forceinline__ float wave_sum(float v) {
  #pragma unroll
  for (int off = 32; off > 0; off >>= 1) v += __shfl_xor(v, off, 64);
  return v;
}
__device__ __forceinline__ float wave_max(float v) {
  #pragma unroll
  for (int off = 32; off > 0; off >>= 1) v = fmaxf(v, __shfl_xor(v, off, 64));
  return v;
}
__device__ __forceinline__ void unpack8(uint4 v, float* f) {
  f[0] = __uint_as_float(v.x << 16); f[1] = __uint_as_float(v.x & 0xFFFF0000u);
  f[2] = __uint_as_float(v.y << 16); f[3] = __uint_as_float(v.y & 0xFFFF0000u);
  f[4] = __uint_as_float(v.z << 16); f[5] = __uint_as_float(v.z & 0xFFFF0000u);
  f[6] = __uint_as_float(v.w << 16); f[7] = __uint_as_float(v.w & 0xFFFF0000u);
}

// ------------------------------------------------------------ dtype probe
__global__ void probe(const u32* __restrict__ g, int* __restrict__ flag) {
  if (threadIdx.x == 0) {
    int ok = 1;
    #pragma unroll
    for (int i = 0; i < 4; i++) {
      u32 w = g[i];
      u32 lo = w & 0xFFFFu, hi = w >> 16;
      ok &= (lo >= 0x3E00u && lo <= 0x4100u) ? 1 : 0;
      ok &= (hi >= 0x3E00u && hi <= 0x4100u) ? 1 : 0;
    }
    *flag = ok ? 0 : 1;  // 0 = bf16 inputs, 1 = f32 inputs
  }
}

// ------------------------------------------------------------ stage inputs -> bf16
__global__ __launch_bounds__(256) void convert_all(
    const void* p0, const void* p1, const void* p2, const void* p3,
    const void* p4, const void* p5, const void* p6, const void* p7,
    const void* p8, const void* p9, const void* p10, const void* p11,
    u16* __restrict__ S, const int* __restrict__ flag) {
  const void* src; int n; int off;
  switch (blockIdx.z) {
    case 0:  src = p0;  n = 1048576; off = S_CEN; break;
    case 1:  src = p1;  n = 8192;    off = S_QW; break;
    case 2:  src = p2;  n = 524288;  off = S_KW; break;
    case 3:  src = p3;  n = 524288;  off = S_VW; break;
    case 4:  src = p4;  n = 36864;   off = S_W1; break;
    case 5:  src = p5;  n = 128;     off = S_B1; break;
    case 6:  src = p6;  n = 1024;    off = S_W2; break;
    case 7:  src = p7;  n = 32;      off = S_B2; break;
    case 8:  src = p8;  n = 8;       off = S_SW; break;
    case 9:  src = p9;  n = 65536;   off = S_OW; break;
    case 10: src = p10; n = 256;     off = S_GAMMA; break;
    default: src = p11; n = 256;     off = S_BETA; break;
  }
  int idx = (blockIdx.x * 256 + threadIdx.x) * 4;
  if (idx >= n) return;
  u16* dst = S + off + idx;
  if (*flag) {
    float4 v = ((const float4*)src)[idx >> 2];
    dst[0] = f2b(v.x); dst[1] = f2b(v.y); dst[2] = f2b(v.z); dst[3] = f2b(v.w);
  } else {
    *(ushort4*)dst = ((const ushort4*)src)[idx >> 2];
  }
}

// -------------------------------------------------------------- sur + cenx -> Mbuf
__global__ __launch_bounds__(256) void sur_all(
    const u16* __restrict__ cen, const u16* __restrict__ w1g,
    const u16* __restrict__ b1g, const u16* __restrict__ w2g,
    const u16* __restrict__ b2g, const u16* __restrict__ swg,
    u16* __restrict__ Mbuf) {
  const int si = blockIdx.z;
  const int d = 1 << si;  // 1,2,4,8
  __shared__ float w1s[9216];  // [tap][ci][co]
  __shared__ float w2s[256];
  __shared__ float b1s[32];
  __shared__ float b2s[8];
  const int t = threadIdx.x;
  for (int e = t; e < 9216; e += 256) {
    int tap = e >> 10, rem = e & 1023, ci = rem >> 5, co = rem & 31;
    w1s[e] = b2f(w1g[si * 9216 + co * 288 + ci * 9 + tap]);
  }
  w2s[t] = b2f(w2g[si * 256 + t]);
  if (t < 32) b1s[t] = b2f(b1g[si * 32 + t]);
  if (t < 8) b2s[t] = b2f(b2g[si * 8 + t]);
  __syncthreads();

  const int b = blockIdx.y;
  const int s = blockIdx.x * 256 + t;
  const int h = s >> 7, w = s & 127;

  float s0 = b2f(swg[si * 2 + 0]), s1 = b2f(swg[si * 2 + 1]);
  float mx = fmaxf(s0, s1);
  float e0 = expf(s0 - mx), e1 = expf(s1 - mx);
  float w20 = e0 / (e0 + e1), w21 = e1 / (e0 + e1);

  const u16* cb = cen + (size_t)b * 32 * HW;

  float h1[32];
  #pragma unroll
  for (int i = 0; i < 32; i++) h1[i] = 0.f;
  for (int tap = 0; tap < 9; tap++) {
    int ky = tap / 3, kx = tap - ky * 3;
    int y = h + (ky - 1) * d, x = w + (kx - 1) * d;
    if (y < 0 || y >= 128 || x < 0 || x >= 128) continue;
    int off = y * 128 + x;
    const float* wt = &w1s[tap * 1024];
    for (int ci = 0; ci < 32; ci++) {
      float v = b2f(cb[(size_t)ci * HW + off]);
      #pragma unroll
      for (int co = 0; co < 32; co++) h1[co] = fmaf(v, wt[ci * 32 + co], h1[co]);
    }
  }
  #pragma unroll
  for (int i = 0; i < 32; i++) h1[i] = fmaxf(h1[i] + b1s[i], 0.f);

  float lg[8];
  #pragma unroll
  for (int k = 0; k < 8; k++) lg[k] = b2s[k];
  for (int ci = 0; ci < 32; ci++) {
    float v = h1[ci];
    #pragma unroll
    for (int k = 0; k < 8; k++) lg[k] = fmaf(v, w2s[k * 32 + ci], lg[k]);
  }
  float lm = lg[0];
  #pragma unroll
  for (int k = 1; k < 8; k++) lm = fmaxf(lm, lg[k]);
  float ls = 0.f;
  #pragma unroll
  for (int k = 0; k < 8; k++) { lg[k] = expf(lg[k] - lm); ls += lg[k]; }
  float inv = w20 / ls;
  #pragma unroll
  for (int k = 0; k < 8; k++) lg[k] *= inv;

  const int dy[8] = {-d, -d, -d, 0, 0, d, d, d};
  const int dx[8] = {-d, 0, d, -d, d, -d, 0, d};
  int offk[8];
  #pragma unroll
  for (int k = 0; k < 8; k++) {
    int y = h + dy[k]; y = y < 0 ? -y : (y > 127 ? 254 - y : y);
    int x = w + dx[k]; x = x < 0 ? -x : (x > 127 ? 254 - x : x);
    offk[k] = y * 128 + x;
  }
  u16* Mb = Mbuf + (size_t)b * 1152 * HW;
  for (int c = 0; c < 32; c++) {
    const u16* cc = cb + (size_t)c * HW;
    float cv = b2f(cc[s]);
    float nb[8];
    #pragma unroll
    for (int k = 0; k < 8; k++) nb[k] = b2f(cc[offk[k]]);
    float sx = 0.f, mn = 0.f;
    #pragma unroll
    for (int k = 0; k < 8; k++) { sx = fmaf(lg[k], nb[k], sx); mn += nb[k]; }
    float sumx = sx + cv * w21;
    Mb[(size_t)(32 * si + c) * HW + s] = f2b(mn * 0.125f * w20 + cv * w21);
    #pragma unroll
    for (int k = 0; k < 8; k++)
      Mb[(size_t)(128 + 256 * si + k * 32 + c) * HW + s] = f2b(nb[k] - sumx);
  }
}

// ------------------------------------ Gram blocks via MFMA (K-split + atomics)
__global__ __launch_bounds__(256) void gram_mfma(
    const u16* __restrict__ Mbuf, float* __restrict__ G) {
  const int tid = blockIdx.x;  // 0..24
  const int ks = blockIdx.y;   // 0..15
  const int b = blockIdx.z;
  int r0, c0, gstride; size_t goff;
  if (tid == 0) { r0 = 0; c0 = 0; goff = G_D1; gstride = 128; }
  else if (tid < 9) { r0 = 0; c0 = 128 * tid; goff = G_D2 + (size_t)(tid - 1) * 128; gstride = 1024; }
  else {
    int t2 = tid - 9; int j = t2 >> 2, p = (t2 >> 1) & 1, q = t2 & 1;
    r0 = 128 + 256 * j + 128 * p; c0 = 128 + 256 * j + 128 * q;
    goff = G_S + (size_t)j * 65536 + p * 128 * 256 + q * 128; gstride = 256;
  }
  const u16* Mb = Mbuf + (size_t)b * 1152 * HW;
  __shared__ u16 As[128][72];  // pad 72: 2-way max on b128 reads
  __shared__ u16 Bs[128][72];
  const int t = threadIdx.x;
  const int lane = t & 63, w = t >> 6;
  const int wr = w >> 1, wc = w & 1;
  const int m = lane & 15, quad = lane >> 4;
  f32x4 acc[4][4];
  #pragma unroll
  for (int i = 0; i < 4; i++)
    #pragma unroll
    for (int j = 0; j < 4; j++) acc[i][j] = (f32x4){0.f, 0.f, 0.f, 0.f};

  for (int s0 = ks * 1024; s0 < ks * 1024 + 1024; s0 += 64) {
    for (int e = t; e < 1024; e += 256) {
      int r = e >> 3, kc8 = (e & 7) * 8;
      *(uint4*)&As[r][kc8] = *(const uint4*)&Mb[(size_t)(r0 + r) * HW + s0 + kc8];
      *(uint4*)&Bs[r][kc8] = *(const uint4*)&Mb[(size_t)(c0 + r) * HW + s0 + kc8];
    }
    __syncthreads();
    #pragma unroll
    for (int k0 = 0; k0 < 64; k0 += 32) {
      short8 af[4], bf[4];
      #pragma unroll
      for (int i = 0; i < 4; i++) af[i] = *(const short8*)&As[wr * 64 + i * 16 + m][k0 + quad * 8];
      #pragma unroll
      for (int j = 0; j < 4; j++) bf[j] = *(const short8*)&Bs[wc * 64 + j * 16 + m][k0 + quad * 8];
      #pragma unroll
      for (int i = 0; i < 4; i++)
        #pragma unroll
        for (int j = 0; j < 4; j++)
          acc[i][j] = __builtin_amdgcn_mfma_f32_16x16x32_bf16(af[i], bf[j], acc[i][j], 0, 0, 0);
    }
    __syncthreads();
  }
  float* Gb = G + (size_t)b * G_SZ + goff;
  #pragma unroll
  for (int i = 0; i < 4; i++)
    #pragma unroll
    for (int j = 0; j < 4; j++) {
      int col = wc * 64 + j * 16 + m;
      #pragma unroll
      for (int r = 0; r < 4; r++) {
        int row = wr * 64 + i * 16 + quad * 4 + r;
        atomicAdd(&Gb[(size_t)row * gstride + col], acc[i][j][r]);
      }
    }
}

// ------------------------------------------------------------------ Q row inv-norms
__global__ __launch_bounds__(64) void qnorm(
    const u16* __restrict__ qw, const float* __restrict__ G,
    float* __restrict__ invQ) {
  const int bn = blockIdx.x, b = bn >> 2, n = bn & 3;
  const int rq = threadIdx.x;
  const int i = rq & 3, q1r = rq >> 2;
  const u16* qr = qw + ((size_t)(i * 64) + 16 * n + q1r) * 32;
  float v[32];
  #pragma unroll
  for (int c = 0; c < 32; c++) v[c] = b2f(qr[c]);
  const float* D1 = G + (size_t)b * G_SZ;
  float ss = 0.f;
  for (int c = 0; c < 32; c++) {
    float tmp = 0.f;
    #pragma unroll
    for (int c2 = 0; c2 < 32; c2++) tmp = fmaf(v[c2], D1[(size_t)(32 * i + c2) * 128 + 32 * i + c], tmp);
    ss = fmaf(tmp, v[c], ss);
  }
  invQ[bn * 64 + rq] = 1.f / fmaxf(sqrtf(fmaxf(ss, 0.f)), 1e-12f);
}

// ------------------------------------------------------------------ K row inv-norms
__global__ __launch_bounds__(256) void knorm(
    const u16* __restrict__ kw, const float* __restrict__ G,
    float* __restrict__ invK) {
  const int rk = blockIdx.x, n = blockIdx.y, b = blockIdx.z;
  const int j = rk & 3, kk = rk >> 2;
  const u16* kr = kw + ((size_t)(j * 512) + 128 * n + kk) * 256;
  __shared__ float vs[256];
  const int t = threadIdx.x;
  vs[t] = b2f(kr[t]);
  __syncthreads();
  const float* S = G + (size_t)b * G_SZ + G_S + (size_t)j * 65536;
  float tmp = 0.f;
  for (int c2 = 0; c2 < 256; c2++) tmp = fmaf(vs[c2], S[(size_t)c2 * 256 + t], tmp);
  tmp *= vs[t];
  tmp = wave_sum(tmp);
  __shared__ float red[4];
  if ((t & 63) == 0) red[t >> 6] = tmp;
  __syncthreads();
  if (t == 0) {
    float tot = fmaxf(red[0] + red[1] + red[2] + red[3], 0.f);
    invK[(size_t)(b * 4 + n) * 512 + rk] = 1.f / fmaxf(sqrtf(tot), 1e-12f);
  }
}

// ------------------- score2: per (j,n,b): KD = D2_j . kw^T, then blockdiag(q_w).KD
__global__ __launch_bounds__(256) void score2(
    const u16* __restrict__ qw, const u16* __restrict__ kw,
    const float* __restrict__ G, float* __restrict__ score) {
  const int j = blockIdx.x, n = blockIdx.y, b = blockIdx.z;
  const float* D2 = G + (size_t)b * G_SZ + G_D2;
  const u16* kwb = kw + ((size_t)(j * 512) + 128 * n) * 256;
  __shared__ float As[64][132];
  __shared__ u16 Bs[64][128];
  __shared__ float KD[128][132];
  __shared__ float qws[64][32];
  const int t = threadIdx.x, tx = t & 15, ty = t >> 4;
  float acc[8][8];
  #pragma unroll
  for (int i = 0; i < 8; i++)
    #pragma unroll
    for (int jj = 0; jj < 8; jj++) acc[i][jj] = 0.f;
  for (int ch0 = 0; ch0 < 256; ch0 += 64) {
    for (int e = t; e < 8192; e += 256) {
      int r = e >> 6, kc = e & 63;
      As[kc][r] = D2[(size_t)r * 1024 + j * 256 + ch0 + kc];
      Bs[kc][r] = kwb[(size_t)r * 256 + ch0 + kc];
    }
    __syncthreads();
    #pragma unroll 4
    for (int kc = 0; kc < 64; kc++) {
      float4 a0 = *(const float4*)&As[kc][ty * 8];
      float4 a1 = *(const float4*)&As[kc][ty * 8 + 4];
      uint4 bv = *(const uint4*)&Bs[kc][tx * 8];
      float a[8] = {a0.x, a0.y, a0.z, a0.w, a1.x, a1.y, a1.z, a1.w};
      float bb[8];
      unpack8(bv, bb);
      #pragma unroll
      for (int i = 0; i < 8; i++)
        #pragma unroll
        for (int jj = 0; jj < 8; jj++) acc[i][jj] = fmaf(a[i], bb[jj], acc[i][jj]);
    }
    __syncthreads();
  }
  #pragma unroll
  for (int i = 0; i < 8; i++)
    #pragma unroll
    for (int jj = 0; jj < 8; jj++) KD[ty * 8 + i][tx * 8 + jj] = acc[i][jj];
  for (int e = t; e < 2048; e += 256) {
    int q = e >> 5, c = e & 31;
    int i = q & 3, q1r = q >> 2;
    qws[q][c] = b2f(qw[((size_t)(i * 64) + 16 * n + q1r) * 32 + c]);
  }
  __syncthreads();
  float* sb = score + (size_t)(b * 4 + n) * 64 * 512;
  for (int e = t; e < 8192; e += 256) {
    int q = e >> 7, kk = e & 127;
    int i = q & 3;
    float s = 0.f;
    #pragma unroll
    for (int c = 0; c < 32; c++) s = fmaf(qws[q][c], KD[i * 32 + c][kk], s);
    sb[(size_t)q * 512 + 4 * kk + j] = s;
  }
}

// ------------------------------------------ scale + InstanceNorm + row softmax
__global__ __launch_bounds__(256) void in_softmax(
    float* __restrict__ score, const float* __restrict__ invQ,
    const float* __restrict__ invK) {
  const int bn = blockIdx.x;
  float* sb = score + (size_t)bn * 64 * 512;
  const float* iQ = invQ + bn * 64;
  const float* iK = invK + bn * 512;
  const int t = threadIdx.x;
  float sum = 0.f, ss = 0.f;
  const float isc = 1.f / 128.f;
  for (int e = t; e < 32768; e += 256) {
    int q = e >> 9, kk = e & 511;
    float v = sb[e] * iQ[q] * iK[kk] * isc;
    sb[e] = v;
    sum += v; ss += v * v;
  }
  __shared__ float red[8];
  sum = wave_sum(sum); ss = wave_sum(ss);
  if ((t & 63) == 0) { red[t >> 6] = sum; red[4 + (t >> 6)] = ss; }
  __syncthreads();
  float mean = (red[0] + red[1] + red[2] + red[3]) * (1.f / 32768.f);
  float var = (red[4] + red[5] + red[6] + red[7]) * (1.f / 32768.f) - mean * mean;
  float istd = rsqrtf(var + 1e-5f);
  const int wv = t >> 6, lane = t & 63;
  for (int r = wv; r < 64; r += 4) {
    float z[8];
    float m = -1e30f;
    #pragma unroll
    for (int j = 0; j < 8; j++) {
      z[j] = (sb[(size_t)r * 512 + lane + 64 * j] - mean) * istd;
      m = fmaxf(m, z[j]);
    }
    m = wave_max(m);
    float sloc = 0.f;
    #pragma unroll
    for (int j = 0; j < 8; j++) { z[j] = expf(z[j] - m); sloc += z[j]; }
    sloc = wave_sum(sloc);
    float rinv = 1.f / sloc;
    #pragma unroll
    for (int j = 0; j < 8; j++) sb[(size_t)r * 512 + lane + 64 * j] = z[j] * rinv;
  }
}

// ------------------------------------------- W2[bn][q][j*256+ch] = attn . v_w
__global__ __launch_bounds__(256) void attnW2(
    const float* __restrict__ attn, const u16* __restrict__ vw,
    float* __restrict__ W2) {
  const int n = blockIdx.x, q0 = blockIdx.y * 8, b = blockIdx.z, bn = b * 4 + n;
  const float* ab = attn + (size_t)bn * 64 * 512;
  const int t = threadIdx.x;
  const int j = t >> 6, lane = t & 63;
  __shared__ float at_s[8][512];
  for (int e = t; e < 4096; e += 256) {
    int qg = e >> 9, kcol = e & 511;
    at_s[qg][kcol] = ab[(size_t)(q0 + qg) * 512 + kcol];
  }
  __syncthreads();
  float acc[8][4];
  #pragma unroll
  for (int qg = 0; qg < 8; qg++)
    #pragma unroll
    for (int cc = 0; cc < 4; cc++) acc[qg][cc] = 0.f;
  for (int kk = 0; kk < 128; kk++) {
    const u16* vrow = vw + ((size_t)(j * 512) + 128 * n + kk) * 256 + lane;
    float v0 = b2f(vrow[0]), v1 = b2f(vrow[64]), v2 = b2f(vrow[128]), v3 = b2f(vrow[192]);
    #pragma unroll
    for (int qg = 0; qg < 8; qg++) {
      float a = at_s[qg][4 * kk + j];
      acc[qg][0] = fmaf(a, v0, acc[qg][0]);
      acc[qg][1] = fmaf(a, v1, acc[qg][1]);
      acc[qg][2] = fmaf(a, v2, acc[qg][2]);
      acc[qg][3] = fmaf(a, v3, acc[qg][3]);
    }
  }
  #pragma unroll
  for (int qg = 0; qg < 8; qg++)
    #pragma unroll
    for (int cc = 0; cc < 4; cc++)
      W2[((size_t)bn * 64 + q0 + qg) * 1024 + j * 256 + lane + 64 * cc] = acc[qg][cc];
}

// ------------------------------------------ Wfin16[b][o][jc] = bf16(out_w . W2)
__global__ __launch_bounds__(256) void wfin_k(
    const u16* __restrict__ ow, const float* __restrict__ W2,
    u16* __restrict__ Wfin16) {
  const int jc = blockIdx.x, b = blockIdx.y;
  __shared__ float col[256];
  const int t = threadIdx.x;
  col[t] = W2[((size_t)b * 256 + t) * 1024 + jc];
  __syncthreads();
  float acc = 0.f;
  const u16* owr = ow + (size_t)t * 256;
  for (int c = 0; c < 256; c++) acc = fmaf(b2f(owr[c]), col[c], acc);
  Wfin16[((size_t)b * 256 + t) * 1024 + jc] = f2b(acc);
}

// -------------------------------------- y = Wfin(bf16) @ sur via MFMA (bf16 out)
__global__ __launch_bounds__(256) void y_gemm_mfma(
    const u16* __restrict__ Wfin16, const u16* __restrict__ Mbuf,
    u16* __restrict__ ybuf) {
  const int b = blockIdx.z, row0 = blockIdx.y * 128, col0 = blockIdx.x * 128;
  __shared__ u16 As[128][72];  // [o-row][k]
  __shared__ u16 Bs[128][72];  // [s-col][k] transposed staging
  const u16* Ab = Wfin16 + (size_t)b * 256 * 1024;
  const u16* Mb = Mbuf + (size_t)b * 1152 * HW + (size_t)128 * HW;
  const int t = threadIdx.x;
  const int lane = t & 63, w = t >> 6;
  const int wr = w >> 1, wc = w & 1;
  const int m = lane & 15, quad = lane >> 4;
  f32x4 acc[4][4];
  #pragma unroll
  for (int i = 0; i < 4; i++)
    #pragma unroll
    for (int j = 0; j < 4; j++) acc[i][j] = (f32x4){0.f, 0.f, 0.f, 0.f};

  for (int k0c = 0; k0c < 1024; k0c += 64) {
    for (int e = t; e < 1024; e += 256) {
      int r = e >> 3, kc8 = (e & 7) * 8;
      *(uint4*)&As[r][kc8] = *(const uint4*)&Ab[(size_t)(row0 + r) * 1024 + k0c + kc8];
    }
    for (int e = t; e < 1024; e += 256) {
      int kc = e >> 4, c8 = (e & 15) * 8;
      uint4 v = *(const uint4*)&Mb[(size_t)(k0c + kc) * HW + col0 + c8];
      u16 tmp[8]; *(uint4*)tmp = v;
      // rotated scalar writes: breaks the 288B-stride bank aliasing (16-way -> 2-way)
      #pragma unroll
      for (int uu = 0; uu < 8; uu++) {
        int u = (uu + lane) & 7;
        Bs[c8 + u][kc] = tmp[u];
      }
    }
    __syncthreads();
    #pragma unroll
    for (int k0 = 0; k0 < 64; k0 += 32) {
      short8 af[4], bf[4];
      #pragma unroll
      for (int i = 0; i < 4; i++) af[i] = *(const short8*)&As[wr * 64 + i * 16 + m][k0 + quad * 8];
      #pragma unroll
      for (int j = 0; j < 4; j++) bf[j] = *(const short8*)&Bs[wc * 64 + j * 16 + m][k0 + quad * 8];
      #pragma unroll
      for (int i = 0; i < 4; i++)
        #pragma unroll
        for (int j = 0; j < 4; j++)
          acc[i][j] = __builtin_amdgcn_mfma_f32_16x16x32_bf16(af[i], bf[j], acc[i][j], 0, 0, 0);
    }
    __syncthreads();
  }
  #pragma unroll
  for (int i = 0; i < 4; i++)
    #pragma unroll
    for (int j = 0; j < 4; j++) {
      int col = col0 + wc * 64 + j * 16 + m;
      #pragma unroll
      for (int r = 0; r < 4; r++) {
        int row = row0 + wr * 64 + i * 16 + quad * 4 + r;
        ybuf[((size_t)b * 256 + row) * HW + col] = f2b(acc[i][j][r]);
      }
    }
}

// ---------------------------------------------------------------- BatchNorm
__global__ __launch_bounds__(256) void bn_stats(
    const u16* __restrict__ y, float* __restrict__ st) {
  const int o = blockIdx.x;
  const int t = threadIdx.x;
  float sum = 0.f, ss = 0.f;
  for (int bb = 0; bb < 2; bb++) {
    const u16* p = y + ((size_t)bb * 256 + o) * HW;
    for (int e = t; e < HW / 8; e += 256) {
      uint4 v = ((const uint4*)p)[e];
      float f[8];
      unpack8(v, f);
      #pragma unroll
      for (int k = 0; k < 8; k++) { sum += f[k]; ss += f[k] * f[k]; }
    }
  }
  __shared__ float red[8];
  sum = wave_sum(sum); ss = wave_sum(ss);
  if ((t & 63) == 0) { red[t >> 6] = sum; red[4 + (t >> 6)] = ss; }
  __syncthreads();
  if (t == 0) {
    float mean = (red[0] + red[1] + red[2] + red[3]) / 32768.f;
    float var = (red[4] + red[5] + red[6] + red[7]) / 32768.f - mean * mean;
    st[o * 2] = mean;
    st[o * 2 + 1] = rsqrtf(var + 1e-5f);
  }
}

__global__ __launch_bounds__(256) void bn_apply(
    const u16* __restrict__ y, const float* __restrict__ st,
    const u16* __restrict__ gamma, const u16* __restrict__ beta,
    const int* __restrict__ flag, void* __restrict__ out) {
  const int idx8 = blockIdx.x * 256 + threadIdx.x;
  const int r = idx8 >> 11;
  const int o = r & 255;
  float mean = st[o * 2], istd = st[o * 2 + 1];
  float g = b2f(gamma[o]), be = b2f(beta[o]);
  uint4 v = ((const uint4*)y)[idx8];
  float f[8];
  unpack8(v, f);
  float rr[8];
  #pragma unroll
  for (int k = 0; k < 8; k++) rr[k] = fmaxf((f[k] - mean) * istd * g + be, 0.f);
  if (*flag) {
    float* of = (float*)out + (size_t)idx8 * 8;
    *(float4*)of = make_float4(rr[0], rr[1], rr[2], rr[3]);
    *(float4*)(of + 4) = make_float4(rr[4], rr[5], rr[6], rr[7]);
  } else {
    u32 p0 = (u32)f2b(rr[0]) | ((u32)f2b(rr[1]) << 16);
    u32 p1 = (u32)f2b(rr[2]) | ((u32)f2b(rr[3]) << 16);
    u32 p2 = (u32)f2b(rr[4]) | ((u32)f2b(rr[5]) << 16);
    u32 p3 = (u32)f2b(rr[6]) | ((u32)f2b(rr[7]) << 16);
    ((uint4*)out)[idx8] = make_uint4(p0, p1, p2, p3);
  }
}

// ----------------------------------------------------------------------------
extern "C" void kernel_launch(void* const* d_in, const int* in_sizes, int n_in,
                              void* d_out, int out_size, void* d_ws, size_t ws_size,
                              hipStream_t stream) {
  float* G     = (float*)d_ws;           // 819,200 f32 (2 x G_SZ)
  float* score = G + 819200;             // 262,144
  float* invQ  = score + 262144;         // 512
  float* invK  = invQ + 512;             // 4,096
  float* W2    = invK + 4096;            // 524,288
  float* Wfin  = W2 + 524288;            // slot reused: u16 Wfin16 (uses half)
  float* bnst  = Wfin + 524288;          // 512
  int* flag    = (int*)(bnst + 512);     // 16
  u16* Sbuf    = (u16*)(flag + 16);      // S_TOTAL u16
  u16* Mbuf    = Sbuf + S_TOTAL;         // 37,748,736 u16
  u16* ybuf    = Mbuf + 37748736;        // 8,388,608 u16
  u16* Wfin16  = (u16*)Wfin;

  probe<<<1, 64, 0, stream>>>((const u32*)d_in[10], flag);
  convert_all<<<dim3(1024, 1, 12), 256, 0, stream>>>(
      d_in[0], d_in[1], d_in[2], d_in[3], d_in[4], d_in[5], d_in[6], d_in[7],
      d_in[8], d_in[9], d_in[10], d_in[11], Sbuf, flag);

  sur_all<<<dim3(64, 2, 4), 256, 0, stream>>>(
      Sbuf + S_CEN, Sbuf + S_W1, Sbuf + S_B1, Sbuf + S_W2, Sbuf + S_B2,
      Sbuf + S_SW, Mbuf);
  hipMemsetAsync(G, 0, 819200 * sizeof(float), stream);
  gram_mfma<<<dim3(25, 16, 2), 256, 0, stream>>>(Mbuf, G);
  qnorm<<<8, 64, 0, stream>>>(Sbuf + S_QW, G, invQ);
  knorm<<<dim3(512, 4, 2), 256, 0, stream>>>(Sbuf + S_KW, G, invK);
  score2<<<dim3(4, 4, 2), 256, 0, stream>>>(Sbuf + S_QW, Sbuf + S_KW, G, score);
  in_softmax<<<8, 256, 0, stream>>>(score, invQ, invK);
  attnW2<<<dim3(4, 8, 2), 256, 0, stream>>>(score, Sbuf + S_VW, W2);
  wfin_k<<<dim3(1024, 2), 256, 0, stream>>>(Sbuf + S_OW, W2, Wfin16);
  y_gemm_mfma<<<dim3(128, 2, 2), 256, 0, stream>>>(Wfin16, Mbuf, ybuf);
  bn_stats<<<256, 256, 0, stream>>>(ybuf, bnst);
  bn_apply<<<4096, 256, 0, stream>>>(ybuf, bnst, Sbuf + S_GAMMA, Sbuf + S_BETA,
                                     flag, d_out);
}